// Round 10
// baseline (243.776 us; speedup 1.0000x reference)
//
#include <hip/hip_runtime.h>
#include <hip/hip_bf16.h>
#include <hip/hip_fp8.h>

// CrossViewContrast: loss = -mean_i( 2*<z1n_i,z2n_i> - log(sum_j exp(2*<z1n_i,z2n_j>) + 1e-8) )
// N=16384, D=128.
// R8 (best): MX-fp8 K=128 MFMA, launch_bounds(256,8): sim 47.7us, total 111.5.
// R9: launch_bounds(256,4) + loss fold -> sim 90us REGRESSION. Same matrix work
//   (MfmaUtil*dur = 13.1us both), VGPR 32 both => (256,4) caused a codegen/
//   schedule pessimization, NOT register squeeze. Fold itself saved ~6us of
//   launch overhead. Conflicts pinned at exactly 4/ds_read_b128.
// R10: R8 loop + (256,8) EXACTLY, plus two disjoint-counter changes:
//   (a) stride-4 granule placement: lo/hi ds_read_b128 pair now lands in bank
//       groups 4 apart (bf16-proven pattern) instead of adjacent -> targets the
//       cross-instruction pipeline conflict (counter: SQ_LDS_BANK_CONFLICT);
//   (b) loss folded into sim via last-block ticket (counter: dispatch count).

#define N_ROWS 16384
#define DIM 128
#define JSPLIT 16
#define COLS_PER_BLOCK (N_ROWS / JSPLIT)   // 1024
#define JCHUNK 32
#define NCHUNK (COLS_PER_BLOCK / JCHUNK)   // 32
#define ROWS_PER_BLOCK 128
#define ITILES (N_ROWS / ROWS_PER_BLOCK)   // 128
#define GRID_TOTAL (ITILES * JSPLIT)       // 2048

// exp(2*sim) = 2^(SCALE*sim); SCALE baked into z1q so MFMA acc is already log2-domain.
#define SCALE 2.8853900817779268f  // 2 * log2(e)

typedef __attribute__((ext_vector_type(8))) int   int8v;   // v8i32: 32 fp8 bytes (MFMA A/B frag)
typedef __attribute__((ext_vector_type(4))) int   int4v;   // one 16B LDS granule
typedef __attribute__((ext_vector_type(4))) float floatx4; // MFMA C/D frag

#if __has_builtin(__builtin_amdgcn_exp2f)
#define EXP2(x) __builtin_amdgcn_exp2f(x)
#else
#define EXP2(x) exp2f(x)
#endif

// fmt 0 = OCP e4m3 for both A and B; scales = e8m0 1.0 in all bytes (identity).
__device__ inline floatx4 mfma_fp8_k128(int8v a, int8v b, floatx4 c) {
  return __builtin_amdgcn_mfma_scale_f32_16x16x128_f8f6f4(
      a, b, c, 0, 0, 0, 0x7F7F7F7F, 0, 0x7F7F7F7F);
}

__device__ inline void gload_lds16(const void* gptr, void* lptr) {
  __builtin_amdgcn_global_load_lds(
      (const __attribute__((address_space(1))) void*)gptr,
      (__attribute__((address_space(3))) void*)lptr, 16, 0, 0);
}

__device__ inline short pack_fp8x2(float x, float y) {
#if __has_builtin(__builtin_amdgcn_cvt_pk_fp8_f32)
  int p = __builtin_amdgcn_cvt_pk_fp8_f32(x, y, 0, false);  // bytes 0,1 of result
  return (short)(p & 0xFFFF);
#else
  __hip_fp8_e4m3 a(x), b(y);
  return (short)((unsigned char)a.__x | ((unsigned short)(unsigned char)b.__x << 8));
#endif
}

// ---------------- Kernel 1: row norms + diagonal + fp8 cast + zero init -----
__global__ __launch_bounds__(256) void norm_kernel(
    const float* __restrict__ z1, const float* __restrict__ z2,
    unsigned char* __restrict__ z1q, unsigned char* __restrict__ z2q,
    float* __restrict__ diag, float* __restrict__ denom,
    unsigned int* __restrict__ ticket) {
  int tid = threadIdx.x;
  int wave = tid >> 6, lane = tid & 63;
  int row = blockIdx.x * 4 + wave;   // one wave per row
  const float2* p1 = (const float2*)(z1 + (size_t)row * DIM);
  const float2* p2 = (const float2*)(z2 + (size_t)row * DIM);
  float2 a = p1[lane], b = p2[lane];
  float s11 = a.x * a.x + a.y * a.y;
  float s22 = b.x * b.x + b.y * b.y;
  float s12 = a.x * b.x + a.y * b.y;
#pragma unroll
  for (int m = 32; m >= 1; m >>= 1) {
    s11 += __shfl_xor(s11, m);
    s22 += __shfl_xor(s22, m);
    s12 += __shfl_xor(s12, m);
  }
  float inv1 = 1.0f / fmaxf(sqrtf(s11), 1e-12f);  // torch F.normalize eps
  float inv2 = 1.0f / fmaxf(sqrtf(s22), 1e-12f);
  float sc1 = inv1 * SCALE;                        // bake exp scale into A side
  // fp8 e4m3 (OCP on gfx950): |z1q| <= SCALE ~ 2.89 << 448 max. k order: 2*lane, 2*lane+1.
  ((short*)(z1q + (size_t)row * DIM))[lane] = pack_fp8x2(a.x * sc1, a.y * sc1);
  ((short*)(z2q + (size_t)row * DIM))[lane] = pack_fp8x2(b.x * inv2, b.y * inv2);
  if (lane == 0) {
    diag[row]  = s12 * inv1 * inv2;  // exact fp32 diagonal
    denom[row] = 0.0f;
  }
  if (blockIdx.x == 0 && tid == 0) ticket[0] = 0u;
}

// ---------------- Kernel 2: sim + denom + (last block) loss -----------------
// R8 loop byte-for-byte except the granule placement. Placement: logical
// granule o of row r stored at physical perm(o)^(r&7), perm(o)=(o>>1)|((o&1)<<2).
// Read (lane q,l15): lo at (q^s), hi at (q^s)^4 -> successive ds_read_b128s
// hit bank-groups 4 apart (the measured-zero bf16 stride), not adjacent.
__global__ __launch_bounds__(256, 8) void sim_kernel(
    const unsigned char* __restrict__ z1q,
    const unsigned char* __restrict__ z2q,
    float* __restrict__ denom, const float* __restrict__ diag,
    unsigned int* __restrict__ ticket, float* __restrict__ out) {
  __shared__ int4v lds[2][JCHUNK * 8];  // 2 x 4 KB
  __shared__ float wred[4];
  __shared__ int last_flag;

  int tid = threadIdx.x;
  int w   = tid >> 6;
  int q   = (tid >> 4) & 3;   // quad within wave
  int l15 = tid & 15;
  int s   = l15 & 7;          // swizzle key
  int itile  = blockIdx.x & (ITILES - 1);
  int jsplit = blockIdx.x >> 7;
  int i0 = itile * ROWS_PER_BLOCK + w * 32;

  const floatx4 ZERO4 = {0.f, 0.f, 0.f, 0.f};

  // A fragments: lane (q,l15) holds bytes [q*32, q*32+32) of row (i0+ii*16+l15).
  int8v afrag[2];
#pragma unroll
  for (int ii = 0; ii < 2; ++ii) {
    const int4v* rp = (const int4v*)(z1q + (size_t)(i0 + ii * 16 + l15) * DIM);
    int4v a0 = rp[q * 2], a1 = rp[q * 2 + 1];
    int8v af;
    af[0] = a0[0]; af[1] = a0[1]; af[2] = a0[2]; af[3] = a0[3];
    af[4] = a1[0]; af[5] = a1[1]; af[6] = a1[2]; af[7] = a1[3];
    afrag[ii] = af;
  }

  floatx4 rowsum[2];
  rowsum[0] = ZERO4;
  rowsum[1] = ZERO4;
  // carried accumulator; seed -1e30 so the first flush adds exp2(-1e30) = 0
  floatx4 pacc = {-1e30f, -1e30f, -1e30f, -1e30f};
  int psel = 1;  // which rowsum the pending pacc belongs to

  const char* Bbase = (const char*)z2q + (size_t)jsplit * COLS_PER_BLOCK * DIM;

  // stage one 4 KB chunk: 256 thr x 16 B, lane-linear LDS dest (constraint).
  // physical slot gl of row holds logical o = inv_perm(gl ^ s_row):
  //   u = gl ^ (row&7); o = 2*(u&3) + (u>>2)
#define STAGE(cidx, bufi)                                                    \
  do {                                                                       \
    const char* _ck = Bbase + (size_t)(cidx) * JCHUNK * DIM;                 \
    char* _dst = (char*)&lds[bufi][0];                                       \
    int _row = tid >> 3, _gl = tid & 7;                                      \
    int _u = _gl ^ (_row & 7);                                               \
    int _o = 2 * (_u & 3) + (_u >> 2);                                       \
    gload_lds16(_ck + (size_t)_row * DIM + _o * 16,                          \
                _dst + (size_t)tid * 16);                                    \
  } while (0)

  STAGE(0, 0);
  __syncthreads();

  int lo_i = q ^ s;       // physical granule of logical 2q
  int hi_i = lo_i ^ 4;    // physical granule of logical 2q+1 (stride-4 apart)

  for (int c = 0; c < NCHUNK; ++c) {
    if (c + 1 < NCHUNK) STAGE(c + 1, (c + 1) & 1);
    const int4v* buf = &lds[c & 1][0];

#pragma unroll
    for (int jj = 0; jj < 2; ++jj) {
      int rbase = (jj * 16 + l15) * 8;
      int4v lo = buf[rbase + lo_i];
      int4v hi = buf[rbase + hi_i];
      int8v bf;
      bf[0] = lo[0]; bf[1] = lo[1]; bf[2] = lo[2]; bf[3] = lo[3];
      bf[4] = hi[0]; bf[5] = hi[1]; bf[6] = hi[2]; bf[7] = hi[3];

#pragma unroll
      for (int ii = 0; ii < 2; ++ii) {
        floatx4 nacc = mfma_fp8_k128(afrag[ii], bf, ZERO4);
        // flush the PREVIOUS tile's accumulator in this MFMA's shadow
        floatx4 e;
#pragma unroll
        for (int r = 0; r < 4; ++r) e[r] = EXP2(pacc[r]);
        rowsum[psel] += e;
        pacc = nacc;
        psel = ii;
      }
    }
    __syncthreads();  // guards buf reuse
  }
  // final flush
  {
    floatx4 e;
#pragma unroll
    for (int r = 0; r < 4; ++r) e[r] = EXP2(pacc[r]);
    rowsum[psel] += e;
  }

  // reduce the 16 column-partials (spread over l15) and commit.
  // C/D layout (shape-determined): col = lane&15 (j), row = q*4 + r (i).
#pragma unroll
  for (int ii = 0; ii < 2; ++ii)
#pragma unroll
    for (int r = 0; r < 4; ++r) {
      float v = rowsum[ii][r];
      v += __shfl_xor(v, 1);
      v += __shfl_xor(v, 2);
      v += __shfl_xor(v, 4);
      v += __shfl_xor(v, 8);
      if (l15 == 0) atomicAdd(&denom[i0 + ii * 16 + q * 4 + r], v);
    }

  // -------- split-K ticket: last block computes the loss ------------------
  __threadfence();   // order this thread's denom atomics before the ticket
  __syncthreads();   // all threads of the block have fenced
  if (tid == 0) {
    unsigned int old = atomicAdd(ticket, 1u);
    last_flag = (old == GRID_TOTAL - 1) ? 1 : 0;
  }
  __syncthreads();
  if (last_flag) {
    __threadfence();  // acquire side
    float acc = 0.f;
#pragma unroll 4
    for (int rr = 0; rr < N_ROWS / 256; ++rr) {
      int row = rr * 256 + tid;
      float d = __hip_atomic_load(&denom[row], __ATOMIC_RELAXED,
                                  __HIP_MEMORY_SCOPE_AGENT);
      float g = diag[row];  // written by norm_kernel (prior dispatch)
      acc += 2.0f * g - __logf(d + 1e-8f);
    }
#pragma unroll
    for (int m = 32; m >= 1; m >>= 1) acc += __shfl_xor(acc, m);
    if ((tid & 63) == 0) wred[tid >> 6] = acc;
    __syncthreads();
    if (tid == 0)
      out[0] = -(wred[0] + wred[1] + wred[2] + wred[3]) * (1.0f / N_ROWS);
  }
}

extern "C" void kernel_launch(void* const* d_in, const int* in_sizes, int n_in,
                              void* d_out, int out_size, void* d_ws, size_t ws_size,
                              hipStream_t stream) {
  const float* z1 = (const float*)d_in[0];
  const float* z2 = (const float*)d_in[1];
  char* ws = (char*)d_ws;
  unsigned char* z1q = (unsigned char*)ws;                                  // 2 MB
  unsigned char* z2q = (unsigned char*)(ws + (size_t)N_ROWS * DIM);         // 2 MB
  float* denom = (float*)(ws + (size_t)2 * N_ROWS * DIM);                   // 64 KB
  float* diag  = (float*)(ws + (size_t)2 * N_ROWS * DIM + (size_t)N_ROWS * 4);
  unsigned int* ticket = (unsigned int*)(ws + (size_t)2 * N_ROWS * DIM + (size_t)N_ROWS * 8);
  float* outp  = (float*)d_out;

  norm_kernel<<<N_ROWS / 4, 256, 0, stream>>>(z1, z2, z1q, z2q, diag, denom, ticket);
  sim_kernel<<<GRID_TOTAL, 256, 0, stream>>>(z1q, z2q, denom, diag, ticket, outp);
}

// Round 11
// 110.450 us; speedup vs baseline: 2.2071x; 2.2071x over previous
//
#include <hip/hip_runtime.h>
#include <hip/hip_bf16.h>
#include <hip/hip_fp8.h>

// CrossViewContrast: loss = -mean_i( 2*<z1n_i,z2n_i> - log(sum_j exp(2*<z1n_i,z2n_j>) + 1e-8) )
// N=16384, D=128.
// R8 (best): MX-fp8 K=128 MFMA, 3 kernels, launch_bounds(256,8): sim 47.7us, total 111.5.
// R9/R10: loss-fold via ticket+__threadfence = 40-140us of TCC stall (device-scope
//   fences from thousands of waves serialize). ABANDONED: stream-ordered separate
//   kernels are the fence-free ordering. R10 DID prove the stride-4 granule
//   placement zeroes SQ_LDS_BANK_CONFLICT (4.19M -> 0, ~1.7us of LDS cycles).
// R11: R8 exact structure + stride-4 placement ONLY.

#define N_ROWS 16384
#define DIM 128
#define JSPLIT 16
#define COLS_PER_BLOCK (N_ROWS / JSPLIT)   // 1024
#define JCHUNK 32
#define NCHUNK (COLS_PER_BLOCK / JCHUNK)   // 32
#define ROWS_PER_BLOCK 128
#define ITILES (N_ROWS / ROWS_PER_BLOCK)   // 128
#define GRID_TOTAL (ITILES * JSPLIT)       // 2048

// exp(2*sim) = 2^(SCALE*sim); SCALE baked into z1q so MFMA acc is already log2-domain.
#define SCALE 2.8853900817779268f  // 2 * log2(e)

typedef __attribute__((ext_vector_type(8))) int   int8v;   // v8i32: 32 fp8 bytes (MFMA A/B frag)
typedef __attribute__((ext_vector_type(4))) int   int4v;   // one 16B LDS granule
typedef __attribute__((ext_vector_type(4))) float floatx4; // MFMA C/D frag

#if __has_builtin(__builtin_amdgcn_exp2f)
#define EXP2(x) __builtin_amdgcn_exp2f(x)
#else
#define EXP2(x) exp2f(x)
#endif

// fmt 0 = OCP e4m3 for both A and B; scales = e8m0 1.0 in all bytes (identity).
__device__ inline floatx4 mfma_fp8_k128(int8v a, int8v b, floatx4 c) {
  return __builtin_amdgcn_mfma_scale_f32_16x16x128_f8f6f4(
      a, b, c, 0, 0, 0, 0x7F7F7F7F, 0, 0x7F7F7F7F);
}

__device__ inline void gload_lds16(const void* gptr, void* lptr) {
  __builtin_amdgcn_global_load_lds(
      (const __attribute__((address_space(1))) void*)gptr,
      (__attribute__((address_space(3))) void*)lptr, 16, 0, 0);
}

__device__ inline short pack_fp8x2(float x, float y) {
#if __has_builtin(__builtin_amdgcn_cvt_pk_fp8_f32)
  int p = __builtin_amdgcn_cvt_pk_fp8_f32(x, y, 0, false);  // bytes 0,1 of result
  return (short)(p & 0xFFFF);
#else
  __hip_fp8_e4m3 a(x), b(y);
  return (short)((unsigned char)a.__x | ((unsigned short)(unsigned char)b.__x << 8));
#endif
}

// ---------------- Kernel 1: row norms + diagonal + fp8 cast + zero init -----
__global__ __launch_bounds__(256) void norm_kernel(
    const float* __restrict__ z1, const float* __restrict__ z2,
    unsigned char* __restrict__ z1q, unsigned char* __restrict__ z2q,
    float* __restrict__ diag, float* __restrict__ denom,
    float* __restrict__ out) {
  int tid = threadIdx.x;
  int wave = tid >> 6, lane = tid & 63;
  int row = blockIdx.x * 4 + wave;   // one wave per row
  const float2* p1 = (const float2*)(z1 + (size_t)row * DIM);
  const float2* p2 = (const float2*)(z2 + (size_t)row * DIM);
  float2 a = p1[lane], b = p2[lane];
  float s11 = a.x * a.x + a.y * a.y;
  float s22 = b.x * b.x + b.y * b.y;
  float s12 = a.x * b.x + a.y * b.y;
#pragma unroll
  for (int m = 32; m >= 1; m >>= 1) {
    s11 += __shfl_xor(s11, m);
    s22 += __shfl_xor(s22, m);
    s12 += __shfl_xor(s12, m);
  }
  float inv1 = 1.0f / fmaxf(sqrtf(s11), 1e-12f);  // torch F.normalize eps
  float inv2 = 1.0f / fmaxf(sqrtf(s22), 1e-12f);
  float sc1 = inv1 * SCALE;                        // bake exp scale into A side
  // fp8 e4m3 (OCP on gfx950): |z1q| <= SCALE ~ 2.89 << 448 max. k order: 2*lane, 2*lane+1.
  ((short*)(z1q + (size_t)row * DIM))[lane] = pack_fp8x2(a.x * sc1, a.y * sc1);
  ((short*)(z2q + (size_t)row * DIM))[lane] = pack_fp8x2(b.x * inv2, b.y * inv2);
  if (lane == 0) {
    diag[row]  = s12 * inv1 * inv2;  // exact fp32 diagonal
    denom[row] = 0.0f;
  }
  if (blockIdx.x == 0 && tid == 0) out[0] = 0.0f;
}

// ---------------- Kernel 2: denom_i += sum_j exp(2*sim_ij), MX-fp8 MFMA -----
// R8 loop byte-for-byte except granule placement. Placement: logical granule o
// of row r stored at physical perm(o)^(r&7), perm(o)=(o>>1)|((o&1)<<2). Read
// (lane q,l15): lo at (q^s), hi at (q^s)^4 -> successive ds_read_b128s hit
// bank-groups 4 apart; R10 measured SQ_LDS_BANK_CONFLICT == 0 with this layout.
__global__ __launch_bounds__(256, 8) void sim_kernel(
    const unsigned char* __restrict__ z1q,
    const unsigned char* __restrict__ z2q,
    float* __restrict__ denom) {
  __shared__ int4v lds[2][JCHUNK * 8];  // 2 x 4 KB

  int tid = threadIdx.x;
  int w   = tid >> 6;
  int q   = (tid >> 4) & 3;   // quad within wave
  int l15 = tid & 15;
  int s   = l15 & 7;          // swizzle key
  int itile  = blockIdx.x & (ITILES - 1);
  int jsplit = blockIdx.x >> 7;
  int i0 = itile * ROWS_PER_BLOCK + w * 32;

  const floatx4 ZERO4 = {0.f, 0.f, 0.f, 0.f};

  // A fragments: lane (q,l15) holds bytes [q*32, q*32+32) of row (i0+ii*16+l15).
  int8v afrag[2];
#pragma unroll
  for (int ii = 0; ii < 2; ++ii) {
    const int4v* rp = (const int4v*)(z1q + (size_t)(i0 + ii * 16 + l15) * DIM);
    int4v a0 = rp[q * 2], a1 = rp[q * 2 + 1];
    int8v af;
    af[0] = a0[0]; af[1] = a0[1]; af[2] = a0[2]; af[3] = a0[3];
    af[4] = a1[0]; af[5] = a1[1]; af[6] = a1[2]; af[7] = a1[3];
    afrag[ii] = af;
  }

  floatx4 rowsum[2];
  rowsum[0] = ZERO4;
  rowsum[1] = ZERO4;
  // carried accumulator; seed -1e30 so the first flush adds exp2(-1e30) = 0
  floatx4 pacc = {-1e30f, -1e30f, -1e30f, -1e30f};
  int psel = 1;  // which rowsum the pending pacc belongs to

  const char* Bbase = (const char*)z2q + (size_t)jsplit * COLS_PER_BLOCK * DIM;

  // stage one 4 KB chunk: 256 thr x 16 B, lane-linear LDS dest (constraint).
  // physical slot gl of row holds logical o = inv_perm(gl ^ (row&7)):
  //   u = gl ^ (row&7); o = 2*(u&3) + (u>>2)
#define STAGE(cidx, bufi)                                                    \
  do {                                                                       \
    const char* _ck = Bbase + (size_t)(cidx) * JCHUNK * DIM;                 \
    char* _dst = (char*)&lds[bufi][0];                                       \
    int _row = tid >> 3, _gl = tid & 7;                                      \
    int _u = _gl ^ (_row & 7);                                               \
    int _o = 2 * (_u & 3) + (_u >> 2);                                       \
    gload_lds16(_ck + (size_t)_row * DIM + _o * 16,                          \
                _dst + (size_t)tid * 16);                                    \
  } while (0)

  STAGE(0, 0);
  __syncthreads();

  int lo_i = q ^ s;       // physical granule of logical 2q
  int hi_i = lo_i ^ 4;    // physical granule of logical 2q+1 (stride-4 apart)

  for (int c = 0; c < NCHUNK; ++c) {
    if (c + 1 < NCHUNK) STAGE(c + 1, (c + 1) & 1);
    const int4v* buf = &lds[c & 1][0];

#pragma unroll
    for (int jj = 0; jj < 2; ++jj) {
      int rbase = (jj * 16 + l15) * 8;
      int4v lo = buf[rbase + lo_i];
      int4v hi = buf[rbase + hi_i];
      int8v bf;
      bf[0] = lo[0]; bf[1] = lo[1]; bf[2] = lo[2]; bf[3] = lo[3];
      bf[4] = hi[0]; bf[5] = hi[1]; bf[6] = hi[2]; bf[7] = hi[3];

#pragma unroll
      for (int ii = 0; ii < 2; ++ii) {
        floatx4 nacc = mfma_fp8_k128(afrag[ii], bf, ZERO4);
        // flush the PREVIOUS tile's accumulator in this MFMA's shadow
        floatx4 e;
#pragma unroll
        for (int r = 0; r < 4; ++r) e[r] = EXP2(pacc[r]);
        rowsum[psel] += e;
        pacc = nacc;
        psel = ii;
      }
    }
    __syncthreads();  // guards buf reuse
  }
  // final flush
  {
    floatx4 e;
#pragma unroll
    for (int r = 0; r < 4; ++r) e[r] = EXP2(pacc[r]);
    rowsum[psel] += e;
  }

  // reduce the 16 column-partials (spread over l15) and commit.
  // C/D layout (shape-determined): col = lane&15 (j), row = q*4 + r (i).
#pragma unroll
  for (int ii = 0; ii < 2; ++ii)
#pragma unroll
    for (int r = 0; r < 4; ++r) {
      float v = rowsum[ii][r];
      v += __shfl_xor(v, 1);
      v += __shfl_xor(v, 2);
      v += __shfl_xor(v, 4);
      v += __shfl_xor(v, 8);
      if (l15 == 0) atomicAdd(&denom[i0 + ii * 16 + q * 4 + r], v);
    }
}

// ---------------- Kernel 3: loss = -mean(2*diag - log(denom+eps)) -----------
// 64 blocks x 256 threads; one row/thread; wave-reduce then one atomicAdd/wave.
__global__ __launch_bounds__(256) void loss_kernel(
    const float* __restrict__ denom, const float* __restrict__ diag,
    float* __restrict__ out) {
  int row = blockIdx.x * 256 + threadIdx.x;
  float t = 2.0f * diag[row] - __logf(denom[row] + 1e-8f);
#pragma unroll
  for (int m = 32; m >= 1; m >>= 1) t += __shfl_xor(t, m);
  if ((threadIdx.x & 63) == 0) atomicAdd(out, -t * (1.0f / N_ROWS));
}

extern "C" void kernel_launch(void* const* d_in, const int* in_sizes, int n_in,
                              void* d_out, int out_size, void* d_ws, size_t ws_size,
                              hipStream_t stream) {
  const float* z1 = (const float*)d_in[0];
  const float* z2 = (const float*)d_in[1];
  char* ws = (char*)d_ws;
  unsigned char* z1q = (unsigned char*)ws;                                  // 2 MB
  unsigned char* z2q = (unsigned char*)(ws + (size_t)N_ROWS * DIM);         // 2 MB
  float* denom = (float*)(ws + (size_t)2 * N_ROWS * DIM);                   // 64 KB
  float* diag  = (float*)(ws + (size_t)2 * N_ROWS * DIM + (size_t)N_ROWS * 4);
  float* outp  = (float*)d_out;

  norm_kernel<<<N_ROWS / 4, 256, 0, stream>>>(z1, z2, z1q, z2q, diag, denom, outp);
  sim_kernel<<<GRID_TOTAL, 256, 0, stream>>>(z1q, z2q, denom);
  loss_kernel<<<N_ROWS / 256, 256, 0, stream>>>(denom, diag, outp);
}